// Round 8
// baseline (1136.232 us; speedup 1.0000x reference)
//
#include <hip/hip_runtime.h>
#include <math.h>

#define PI_D 3.14159265358979323846

// ---- workspace float offsets ----
#define OFF_TW   0u
#define OFF_X0   4096u
#define OFF_PWT  OFF_X0                           // alias: X0 dead after k_layer0; 3*16384
#define OFF_TWT  (OFF_X0 + 49152u)                // 32*128, also inside X0 region
#define OFF_WT   (OFF_X0 + 262144u)
#define OFF_XFR  (OFF_WT + 1572864u)
#define OFF_XFI  (OFF_XFR + 4194304u)
#define OFF_OFR  (OFF_XFI + 4194304u)
#define OFF_OFI  (OFF_OFR + 4194304u)
#define OFF_A    (OFF_OFI + 4194304u)
#define OFF_HP   OFF_XFR                          // 64 * 262144 floats, spans XFR..A

__device__ __forceinline__ float gelu_f(float x) {
    return 0.5f * x * (1.0f + erff(x * 0.7071067811865476f));
}

// XOR bank swizzle: float4-chunk index c4 -> float column of its swizzled slot.
__device__ __forceinline__ int swzc(int c4) { return 4 * (c4 ^ ((c4 >> 3) & 3)); }

__global__ void k_setup(float* ws) {
    int id = blockIdx.x * 256 + threadIdx.x;
    if (id < 4096) {
        int l = id >> 5, c = id & 31, m = c & 15;
        double ang = (PI_D / 64.0) * (double)((m * l) & 127);
        double v = (c < 16) ? cos(ang) : -sin(ang);
        ws[OFF_TW + id] = (float)v;
    }
}

__global__ void k_transpose(const float* w1r, const float* w1i,
                            const float* w2r, const float* w2i,
                            const float* w3r, const float* w3i, float* ws) {
    int id = blockIdx.x * 256 + threadIdx.x;
    int lay = id >> 18;
    int rem = id & 262143;
    int m = rem >> 14, i = (rem >> 7) & 127, o = rem & 127;
    const float* sr = (lay == 0) ? w1r : (lay == 1) ? w2r : w3r;
    const float* si = (lay == 0) ? w1i : (lay == 1) ? w2i : w3i;
    int src = (i * 128 + o) * 16 + m;
    ws[OFF_WT + (unsigned)lay * 524288u + rem] = sr[src];
    ws[OFF_WT + (unsigned)lay * 524288u + 262144u + rem] = si[src];
}

// After k_layer0 (X0 dead): pwT[lay][i][o] = w[o][i]; TWT[c][l] = TW[l][c]
__global__ void k_prep2(const float* w1w, const float* w2w, const float* w3w, float* ws) {
    int id = blockIdx.x * 256 + threadIdx.x;
    if (id < 49152) {
        int lay = id >> 14, rem = id & 16383;
        int i = rem >> 7, o = rem & 127;
        const float* w = (lay == 0) ? w1w : (lay == 1) ? w2w : w3w;
        ws[OFF_PWT + id] = w[o * 128 + i];
    } else if (id < 53248) {
        int id2 = id - 49152;
        int c = id2 >> 7, l = id2 & 127;
        ws[OFF_TWT + c * 128 + l] = ws[OFF_TW + l * 32 + c];
    }
}

__global__ __launch_bounds__(256) void k_fc0(const float* X1, const float* w, const float* bias, float* ws) {
    __shared__ float xs[16][128];
    __shared__ float wsm[128][129];
    int t = threadIdx.x;
    int b0 = blockIdx.x * 16;
#pragma unroll
    for (int q = 0; q < 8; ++q) {
        int idx = q * 256 + t;
        xs[idx >> 7][idx & 127] = X1[b0 * 128 + idx];
    }
#pragma unroll
    for (int q = 0; q < 64; ++q) {
        int idx = q * 256 + t;
        wsm[idx >> 7][idx & 127] = w[idx];
    }
    __syncthreads();
    int c = t & 127, bh = t >> 7;
    float* x0 = ws + OFF_X0;
    for (int j = 0; j < 8; ++j) {
        int b = bh * 8 + j;
        float acc = bias[c];
#pragma unroll 8
        for (int k = 0; k < 128; ++k) acc += xs[b][k] * wsm[c][k];
        x0[(b0 + b) * 128 + c] = acc;
    }
}

__global__ __launch_bounds__(256) void k_layer0(const float* w0r, const float* w0i,
                                                const float* w0w, const float* w0b, float* ws) {
    __shared__ float x0s[128];
    __shared__ float tws[128][33];
    __shared__ float xrs[16], xis[16];
    __shared__ __align__(16) float ors[2048];
    __shared__ __align__(16) float ois[2048];
    int t = threadIdx.x, b = blockIdx.x;
    const float* tw = ws + OFF_TW;
    const float* x0 = ws + OFF_X0;
    if (t < 128) x0s[t] = x0[b * 128 + t];
#pragma unroll
    for (int q = 0; q < 16; ++q) {
        int idx = q * 256 + t;
        tws[idx >> 5][idx & 31] = tw[idx];
    }
    __syncthreads();
    if (t < 32) {
        float acc = 0.f;
        for (int l = 0; l < 128; ++l) acc += x0s[l] * tws[l][t];
        if (t < 16) xrs[t] = acc; else xis[t - 16] = acc;
    }
    __syncthreads();
#pragma unroll
    for (int q = 0; q < 8; ++q) {
        int idx = q * 256 + t;
        int m = idx & 15;
        float wr = w0r[idx], wi = w0i[idx];
        float sc = (m == 0) ? (1.f / 128.f) : (2.f / 128.f);
        float xr = xrs[m], xi = xis[m];
        ors[idx] = (xr * wr - xi * wi) * sc;
        ois[idx] = (xr * wi + xi * wr) * sc;
    }
    __syncthreads();
    int l = t & 127, og = t >> 7;
    float tvc[16], tvs[16];
#pragma unroll
    for (int m = 0; m < 16; ++m) { tvc[m] = tws[l][m]; tvs[m] = tws[l][16 + m]; }
    float xl = x0s[l];
    float* A = ws + OFF_A + b * 16384;
    const float4* or4 = (const float4*)ors;
    const float4* oi4 = (const float4*)ois;
    for (int oj = 0; oj < 64; ++oj) {
        int o = og * 64 + oj;
        float acc = xl * w0w[o] + w0b[o];
#pragma unroll
        for (int q = 0; q < 4; ++q) {
            float4 r4 = or4[o * 4 + q];
            float4 i4 = oi4[o * 4 + q];
            acc += r4.x * tvc[4 * q + 0] + i4.x * tvs[4 * q + 0];
            acc += r4.y * tvc[4 * q + 1] + i4.y * tvs[4 * q + 1];
            acc += r4.z * tvc[4 * q + 2] + i4.z * tvs[4 * q + 2];
            acc += r4.w * tvc[4 * q + 3] + i4.w * tvs[4 * q + 3];
        }
        A[o * 128 + l] = gelu_f(acc);
    }
}

// DFT GEMM: 256 rows x 32 cols per block, 128 threads, 8x8 per thread, swizzled LDS.
__global__ __launch_bounds__(128) void k_dft(float* ws) {
    __shared__ float as_[16][260];
    __shared__ float tws_[16][32];
    int t = threadIdx.x;
    int row0 = blockIdx.x * 256;
    const float* A = ws + OFF_A;
    const float* tw = ws + OFF_TW;
    int tr = t >> 2, tc = t & 3;
    float acc[8][8];
#pragma unroll
    for (int j = 0; j < 8; ++j)
#pragma unroll
        for (int cc = 0; cc < 8; ++cc) acc[j][cc] = 0.f;
    int col0 = swzc(2 * tr), col1 = swzc(2 * tr + 1);
    for (int kc = 0; kc < 8; ++kc) {
        int k0 = kc * 16;
        if (kc) __syncthreads();
#pragma unroll
        for (int q = 0; q < 8; ++q) {
            int idx = q * 128 + t;
            int r = idx >> 2, kq = idx & 3;
            float4 v = *(const float4*)&A[(row0 + r) * 128 + k0 + 4 * kq];
            int sc = swzc(r >> 2) + (r & 3);
            as_[4 * kq + 0][sc] = v.x; as_[4 * kq + 1][sc] = v.y;
            as_[4 * kq + 2][sc] = v.z; as_[4 * kq + 3][sc] = v.w;
        }
#pragma unroll
        for (int q = 0; q < 4; ++q) {
            int idx = q * 128 + t;
            tws_[idx >> 5][idx & 31] = tw[(k0 + (idx >> 5)) * 32 + (idx & 31)];
        }
        __syncthreads();
#pragma unroll 8
        for (int kk = 0; kk < 16; ++kk) {
            float4 a0 = *(const float4*)&as_[kk][col0];
            float4 a1 = *(const float4*)&as_[kk][col1];
            float4 t0 = *(const float4*)&tws_[kk][tc * 8];
            float4 t1 = *(const float4*)&tws_[kk][tc * 8 + 4];
            float av[8] = {a0.x,a0.y,a0.z,a0.w,a1.x,a1.y,a1.z,a1.w};
            float tv[8] = {t0.x,t0.y,t0.z,t0.w,t1.x,t1.y,t1.z,t1.w};
#pragma unroll
            for (int j = 0; j < 8; ++j)
#pragma unroll
                for (int cc = 0; cc < 8; ++cc) acc[j][cc] += av[j] * tv[cc];
        }
    }
    float* xfr = ws + OFF_XFR;
    float* xfi = ws + OFF_XFI;
#pragma unroll
    for (int cc = 0; cc < 8; ++cc) {
        int c = tc * 8 + cc;
        float* dst = (c < 16) ? (xfr + c * 262144) : (xfi + (c - 16) * 262144);
        float4 v0 = make_float4(acc[0][cc], acc[1][cc], acc[2][cc], acc[3][cc]);
        float4 v1 = make_float4(acc[4][cc], acc[5][cc], acc[6][cc], acc[7][cc]);
        *(float4*)&dst[row0 + tr * 8] = v0;
        *(float4*)&dst[row0 + tr * 8 + 4] = v1;
    }
}

// Per-mode complex GEMM: 64 b x 128 o, 4x8 complex/thread, double-buffered 16-k chunks.
// Buffer layout in smem: xr[2]@{0,1088}, xi[2]@{2176,3264}, wr[2]@{4352,6464}, wi[2]@{8576,10688}
__global__ __launch_bounds__(256) void k_modemix(int lay, float* ws) {
    __shared__ float smem[12800];
    int t = threadIdx.x;
    int b0 = blockIdx.x * 64;
    int m = blockIdx.y;
    const float* xfr = ws + OFF_XFR + m * 262144;
    const float* xfi = ws + OFF_XFI + m * 262144;
    const float* wtr = ws + OFF_WT + (unsigned)lay * 524288u + m * 16384;
    const float* wti = wtr + 262144;
    int tb = t >> 4, tc = t & 15;
    int wc0 = swzc(2 * tc), wc1 = swzc(2 * tc + 1);
    int xr_ = t >> 2, xkq = t & 3;
    int wk0 = t >> 5, wo0 = t & 31;
    int wk1 = 8 + wk0;
    int wsl = swzc(wo0);
    float accr[4][8], acci[4][8];
#pragma unroll
    for (int jb = 0; jb < 4; ++jb)
#pragma unroll
        for (int jc = 0; jc < 8; ++jc) { accr[jb][jc] = 0.f; acci[jb][jc] = 0.f; }
    float4 vxr = *(const float4*)&xfr[(b0 + xr_) * 128 + 4 * xkq];
    float4 vxi = *(const float4*)&xfi[(b0 + xr_) * 128 + 4 * xkq];
    float4 vwr0 = *(const float4*)&wtr[wk0 * 128 + 4 * wo0];
    float4 vwr1 = *(const float4*)&wtr[wk1 * 128 + 4 * wo0];
    float4 vwi0 = *(const float4*)&wti[wk0 * 128 + 4 * wo0];
    float4 vwi1 = *(const float4*)&wti[wk1 * 128 + 4 * wo0];
    {
        float* xr = smem; float* xi = smem + 2176;
        xr[(4*xkq+0)*68 + xr_] = vxr.x; xr[(4*xkq+1)*68 + xr_] = vxr.y;
        xr[(4*xkq+2)*68 + xr_] = vxr.z; xr[(4*xkq+3)*68 + xr_] = vxr.w;
        xi[(4*xkq+0)*68 + xr_] = vxi.x; xi[(4*xkq+1)*68 + xr_] = vxi.y;
        xi[(4*xkq+2)*68 + xr_] = vxi.z; xi[(4*xkq+3)*68 + xr_] = vxi.w;
        *(float4*)&smem[4352 + wk0 * 132 + wsl] = vwr0;
        *(float4*)&smem[4352 + wk1 * 132 + wsl] = vwr1;
        *(float4*)&smem[8576 + wk0 * 132 + wsl] = vwi0;
        *(float4*)&smem[8576 + wk1 * 132 + wsl] = vwi1;
    }
    __syncthreads();
    for (int ch = 0; ch < 8; ++ch) {
        int xo = (ch & 1) * 1088;
        int wo = (ch & 1) * 2112;
        const float* cxr = smem + xo;
        const float* cxi = smem + 2176 + xo;
        const float* cwr = smem + 4352 + wo;
        const float* cwi = smem + 8576 + wo;
        if (ch < 7) {
            int k0 = (ch + 1) * 16;
            vxr = *(const float4*)&xfr[(b0 + xr_) * 128 + k0 + 4 * xkq];
            vxi = *(const float4*)&xfi[(b0 + xr_) * 128 + k0 + 4 * xkq];
            vwr0 = *(const float4*)&wtr[(k0 + wk0) * 128 + 4 * wo0];
            vwr1 = *(const float4*)&wtr[(k0 + wk1) * 128 + 4 * wo0];
            vwi0 = *(const float4*)&wti[(k0 + wk0) * 128 + 4 * wo0];
            vwi1 = *(const float4*)&wti[(k0 + wk1) * 128 + 4 * wo0];
        }
#pragma unroll 4
        for (int kk = 0; kk < 16; ++kk) {
            float4 xr4 = *(const float4*)&cxr[kk * 68 + tb * 4];
            float4 xi4 = *(const float4*)&cxi[kk * 68 + tb * 4];
            float4 wr0 = *(const float4*)&cwr[kk * 132 + wc0];
            float4 wr1 = *(const float4*)&cwr[kk * 132 + wc1];
            float4 wi0 = *(const float4*)&cwi[kk * 132 + wc0];
            float4 wi1 = *(const float4*)&cwi[kk * 132 + wc1];
            float xrv[4] = {xr4.x, xr4.y, xr4.z, xr4.w};
            float xiv[4] = {xi4.x, xi4.y, xi4.z, xi4.w};
            float wrv[8] = {wr0.x,wr0.y,wr0.z,wr0.w,wr1.x,wr1.y,wr1.z,wr1.w};
            float wiv[8] = {wi0.x,wi0.y,wi0.z,wi0.w,wi1.x,wi1.y,wi1.z,wi1.w};
#pragma unroll
            for (int jb = 0; jb < 4; ++jb)
#pragma unroll
                for (int jc = 0; jc < 8; ++jc) {
                    accr[jb][jc] += xrv[jb] * wrv[jc] - xiv[jb] * wiv[jc];
                    acci[jb][jc] += xrv[jb] * wiv[jc] + xiv[jb] * wrv[jc];
                }
        }
        if (ch < 7) {
            int nxo = ((ch & 1) ^ 1) * 1088;
            int nwo = ((ch & 1) ^ 1) * 2112;
            float* nxr = smem + nxo;
            float* nxi = smem + 2176 + nxo;
            nxr[(4*xkq+0)*68 + xr_] = vxr.x; nxr[(4*xkq+1)*68 + xr_] = vxr.y;
            nxr[(4*xkq+2)*68 + xr_] = vxr.z; nxr[(4*xkq+3)*68 + xr_] = vxr.w;
            nxi[(4*xkq+0)*68 + xr_] = vxi.x; nxi[(4*xkq+1)*68 + xr_] = vxi.y;
            nxi[(4*xkq+2)*68 + xr_] = vxi.z; nxi[(4*xkq+3)*68 + xr_] = vxi.w;
            *(float4*)&smem[4352 + nwo + wk0 * 132 + wsl] = vwr0;
            *(float4*)&smem[4352 + nwo + wk1 * 132 + wsl] = vwr1;
            *(float4*)&smem[8576 + nwo + wk0 * 132 + wsl] = vwi0;
            *(float4*)&smem[8576 + nwo + wk1 * 132 + wsl] = vwi1;
            __syncthreads();
        }
    }
    float* ofr = ws + OFF_OFR + m * 262144;
    float* ofi = ws + OFF_OFI + m * 262144;
#pragma unroll
    for (int jb = 0; jb < 4; ++jb) {
        int b = b0 + tb * 4 + jb;
        float4 r0 = make_float4(accr[jb][0], accr[jb][1], accr[jb][2], accr[jb][3]);
        float4 r1 = make_float4(accr[jb][4], accr[jb][5], accr[jb][6], accr[jb][7]);
        float4 i0 = make_float4(acci[jb][0], acci[jb][1], acci[jb][2], acci[jb][3]);
        float4 i1 = make_float4(acci[jb][4], acci[jb][5], acci[jb][6], acci[jb][7]);
        *(float4*)&ofr[b * 128 + tc * 8]     = r0;
        *(float4*)&ofr[b * 128 + tc * 8 + 4] = r1;
        *(float4*)&ofi[b * 128 + tc * 8]     = i0;
        *(float4*)&ofi[b * 128 + tc * 8 + 4] = i1;
    }
}

// iDFT (prologue, acc init) + pointwise GEMM double-buffered + bias (+gelu), in-place over A.
// Phase-2 buffers: as[2]@{0,2112}, wx[2]@{4224,6336}
template <int GELU>
__global__ __launch_bounds__(256) void k_layerB(const float* pwt, const float* pw_b, float* ws) {
    __shared__ float smem[8448];
    int t = threadIdx.x, b = blockIdx.x;
    float* A = ws + OFF_A + (unsigned)b * 16384u;
    const float* ofr = ws + OFF_OFR;
    const float* ofi = ws + OFF_OFI;
    const float* twt = ws + OFF_TWT;
    int ty = t >> 4, tx = t & 15;
    int col0 = swzc(2 * tx), col1 = swzc(2 * tx + 1);
    int r0 = t >> 5, r1 = 8 + (t >> 5), lq = t & 31;
    int wslot = swzc(lq);
    float4 pa0 = *(const float4*)&A[r0 * 128 + 4 * lq];
    float4 pa1 = *(const float4*)&A[r1 * 128 + 4 * lq];
    float4 pw0 = *(const float4*)&pwt[r0 * 128 + 4 * lq];
    float4 pw1 = *(const float4*)&pwt[r1 * 128 + 4 * lq];
    float* ofr_s = smem;
    float* ofi_s = smem + 2048;
    float* twTs  = smem + 4096;
#pragma unroll
    for (int q = 0; q < 2; ++q) {
        int idx = q * 256 + t;
        int mm = idx >> 5, oq = idx & 31;
        float sc = (mm == 0) ? (1.f / 128.f) : (2.f / 128.f);
        float4 vr = *(const float4*)&ofr[mm * 262144 + b * 128 + 4 * oq];
        float4 vi = *(const float4*)&ofi[mm * 262144 + b * 128 + 4 * oq];
        vr.x *= sc; vr.y *= sc; vr.z *= sc; vr.w *= sc;
        vi.x *= sc; vi.y *= sc; vi.z *= sc; vi.w *= sc;
        *(float4*)&ofr_s[mm * 128 + 4 * oq] = vr;
        *(float4*)&ofi_s[mm * 128 + 4 * oq] = vi;
    }
#pragma unroll
    for (int q = 0; q < 4; ++q) {
        int idx = q * 256 + t;
        int row = idx >> 5, c4 = idx & 31;
        *(float4*)&twTs[row * 132 + swzc(c4)] = *(const float4*)&twt[row * 128 + 4 * c4];
    }
    __syncthreads();
    float acc[8][8];
#pragma unroll
    for (int jo = 0; jo < 8; ++jo)
#pragma unroll
        for (int jl = 0; jl < 8; ++jl) acc[jo][jl] = 0.f;
#pragma unroll 2
    for (int m = 0; m < 16; ++m) {
        float4 or0 = *(const float4*)&ofr_s[m * 128 + ty * 8];
        float4 or1 = *(const float4*)&ofr_s[m * 128 + ty * 8 + 4];
        float4 oi0 = *(const float4*)&ofi_s[m * 128 + ty * 8];
        float4 oi1 = *(const float4*)&ofi_s[m * 128 + ty * 8 + 4];
        float4 c0 = *(const float4*)&twTs[m * 132 + col0];
        float4 c1 = *(const float4*)&twTs[m * 132 + col1];
        float4 s0 = *(const float4*)&twTs[(16 + m) * 132 + col0];
        float4 s1 = *(const float4*)&twTs[(16 + m) * 132 + col1];
        float orv[8] = {or0.x,or0.y,or0.z,or0.w,or1.x,or1.y,or1.z,or1.w};
        float oiv[8] = {oi0.x,oi0.y,oi0.z,oi0.w,oi1.x,oi1.y,oi1.z,oi1.w};
        float cv[8]  = {c0.x,c0.y,c0.z,c0.w,c1.x,c1.y,c1.z,c1.w};
        float sv[8]  = {s0.x,s0.y,s0.z,s0.w,s1.x,s1.y,s1.z,s1.w};
#pragma unroll
        for (int jo = 0; jo < 8; ++jo)
#pragma unroll
            for (int jl = 0; jl < 8; ++jl) acc[jo][jl] += orv[jo] * cv[jl] + oiv[jo] * sv[jl];
    }
    __syncthreads();
    *(float4*)&smem[r0 * 132 + wslot] = pa0;
    *(float4*)&smem[r1 * 132 + wslot] = pa1;
    *(float4*)&smem[4224 + r0 * 132 + 4 * lq] = pw0;
    *(float4*)&smem[4224 + r1 * 132 + 4 * lq] = pw1;
    __syncthreads();
    for (int ch = 0; ch < 8; ++ch) {
        int bo = (ch & 1) * 2112;
        const float* cas = smem + bo;
        const float* cwx = smem + 4224 + bo;
        if (ch < 7) {
            int i0 = (ch + 1) * 16;
            pa0 = *(const float4*)&A[(i0 + r0) * 128 + 4 * lq];
            pa1 = *(const float4*)&A[(i0 + r1) * 128 + 4 * lq];
            pw0 = *(const float4*)&pwt[(i0 + r0) * 128 + 4 * lq];
            pw1 = *(const float4*)&pwt[(i0 + r1) * 128 + 4 * lq];
        }
#pragma unroll 4
        for (int ic = 0; ic < 16; ++ic) {
            float4 a0 = *(const float4*)&cas[ic * 132 + col0];
            float4 a1 = *(const float4*)&cas[ic * 132 + col1];
            float4 w0 = *(const float4*)&cwx[ic * 132 + ty * 8];
            float4 w1 = *(const float4*)&cwx[ic * 132 + ty * 8 + 4];
            float av[8] = {a0.x,a0.y,a0.z,a0.w,a1.x,a1.y,a1.z,a1.w};
            float wv[8] = {w0.x,w0.y,w0.z,w0.w,w1.x,w1.y,w1.z,w1.w};
#pragma unroll
            for (int jo = 0; jo < 8; ++jo)
#pragma unroll
                for (int jl = 0; jl < 8; ++jl) acc[jo][jl] += wv[jo] * av[jl];
        }
        if (ch < 7) {
            int nbo = ((ch & 1) ^ 1) * 2112;
            *(float4*)&smem[nbo + r0 * 132 + wslot] = pa0;
            *(float4*)&smem[nbo + r1 * 132 + wslot] = pa1;
            *(float4*)&smem[4224 + nbo + r0 * 132 + 4 * lq] = pw0;
            *(float4*)&smem[4224 + nbo + r1 * 132 + 4 * lq] = pw1;
            __syncthreads();
        }
    }
#pragma unroll
    for (int jo = 0; jo < 8; ++jo) {
        int o = ty * 8 + jo;
        float bv = pw_b[o];
        float v[8];
#pragma unroll
        for (int jl = 0; jl < 8; ++jl) {
            float x = acc[jo][jl] + bv;
            v[jl] = GELU ? gelu_f(x) : x;
        }
        *(float4*)&A[o * 128 + tx * 8]     = make_float4(v[0], v[1], v[2], v[3]);
        *(float4*)&A[o * 128 + tx * 8 + 4] = make_float4(v[4], v[5], v[6], v[7]);
    }
}

// fc1 split-K: 128x128 tile, 8x8/thread, split-K=64; double-buffered 16-k chunks.
// Buffers: a[2]@{0,2112}, w[2]@{4224,6336}
__global__ __launch_bounds__(256) void k_fc12(const float* fc1w, float* ws) {
    __shared__ float smem[8448];
    int t = threadIdx.x;
    int b0 = blockIdx.x * 128;
    int kz = blockIdx.y;
    const float* A = ws + OFF_A;
    int tm = t >> 4, tn = t & 15;
    int ac0 = swzc(2 * tm), ac1 = swzc(2 * tm + 1);
    int wc0 = swzc(2 * tn), wc1 = swzc(2 * tn + 1);
    int rr0 = t >> 2, rr1 = 64 + (t >> 2), kq = t & 3;
    int sl0 = swzc(rr0 >> 2) + (rr0 & 3);
    int sl1 = swzc(rr1 >> 2) + (rr1 & 3);
    float acc[8][8];
#pragma unroll
    for (int jb = 0; jb < 8; ++jb)
#pragma unroll
        for (int jc = 0; jc < 8; ++jc) acc[jb][jc] = 0.f;
    int kbase = kz * 256;
    float4 va0 = *(const float4*)&A[(b0 + rr0) * 16384 + kbase + 4 * kq];
    float4 va1 = *(const float4*)&A[(b0 + rr1) * 16384 + kbase + 4 * kq];
    float4 vw0 = *(const float4*)&fc1w[rr0 * 16384 + kbase + 4 * kq];
    float4 vw1 = *(const float4*)&fc1w[rr1 * 16384 + kbase + 4 * kq];
    {
        smem[(4*kq+0)*132 + sl0] = va0.x; smem[(4*kq+1)*132 + sl0] = va0.y;
        smem[(4*kq+2)*132 + sl0] = va0.z; smem[(4*kq+3)*132 + sl0] = va0.w;
        smem[(4*kq+0)*132 + sl1] = va1.x; smem[(4*kq+1)*132 + sl1] = va1.y;
        smem[(4*kq+2)*132 + sl1] = va1.z; smem[(4*kq+3)*132 + sl1] = va1.w;
        smem[4224 + (4*kq+0)*132 + sl0] = vw0.x; smem[4224 + (4*kq+1)*132 + sl0] = vw0.y;
        smem[4224 + (4*kq+2)*132 + sl0] = vw0.z; smem[4224 + (4*kq+3)*132 + sl0] = vw0.w;
        smem[4224 + (4*kq+0)*132 + sl1] = vw1.x; smem[4224 + (4*kq+1)*132 + sl1] = vw1.y;
        smem[4224 + (4*kq+2)*132 + sl1] = vw1.z; smem[4224 + (4*kq+3)*132 + sl1] = vw1.w;
    }
    __syncthreads();
    for (int ks = 0; ks < 16; ++ks) {
        int bo = (ks & 1) * 2112;
        const float* ca = smem + bo;
        const float* cw = smem + 4224 + bo;
        if (ks < 15) {
            int k0 = kbase + (ks + 1) * 16;
            va0 = *(const float4*)&A[(b0 + rr0) * 16384 + k0 + 4 * kq];
            va1 = *(const float4*)&A[(b0 + rr1) * 16384 + k0 + 4 * kq];
            vw0 = *(const float4*)&fc1w[rr0 * 16384 + k0 + 4 * kq];
            vw1 = *(const float4*)&fc1w[rr1 * 16384 + k0 + 4 * kq];
        }
#pragma unroll 4
        for (int kk = 0; kk < 16; ++kk) {
            float4 a0 = *(const float4*)&ca[kk * 132 + ac0];
            float4 a1 = *(const float4*)&ca[kk * 132 + ac1];
            float4 w0 = *(const float4*)&cw[kk * 132 + wc0];
            float4 w1 = *(const float4*)&cw[kk * 132 + wc1];
            float av[8] = {a0.x,a0.y,a0.z,a0.w,a1.x,a1.y,a1.z,a1.w};
            float wv[8] = {w0.x,w0.y,w0.z,w0.w,w1.x,w1.y,w1.z,w1.w};
#pragma unroll
            for (int jb = 0; jb < 8; ++jb)
#pragma unroll
                for (int jc = 0; jc < 8; ++jc) acc[jb][jc] += av[jb] * wv[jc];
        }
        if (ks < 15) {
            int nbo = ((ks & 1) ^ 1) * 2112;
            smem[nbo + (4*kq+0)*132 + sl0] = va0.x; smem[nbo + (4*kq+1)*132 + sl0] = va0.y;
            smem[nbo + (4*kq+2)*132 + sl0] = va0.z; smem[nbo + (4*kq+3)*132 + sl0] = va0.w;
            smem[nbo + (4*kq+0)*132 + sl1] = va1.x; smem[nbo + (4*kq+1)*132 + sl1] = va1.y;
            smem[nbo + (4*kq+2)*132 + sl1] = va1.z; smem[nbo + (4*kq+3)*132 + sl1] = va1.w;
            smem[4224 + nbo + (4*kq+0)*132 + sl0] = vw0.x; smem[4224 + nbo + (4*kq+1)*132 + sl0] = vw0.y;
            smem[4224 + nbo + (4*kq+2)*132 + sl0] = vw0.z; smem[4224 + nbo + (4*kq+3)*132 + sl0] = vw0.w;
            smem[4224 + nbo + (4*kq+0)*132 + sl1] = vw1.x; smem[4224 + nbo + (4*kq+1)*132 + sl1] = vw1.y;
            smem[4224 + nbo + (4*kq+2)*132 + sl1] = vw1.z; smem[4224 + nbo + (4*kq+3)*132 + sl1] = vw1.w;
            __syncthreads();
        }
    }
    float* hp = ws + OFF_HP + kz * 262144;
#pragma unroll
    for (int jb = 0; jb < 8; ++jb) {
        int b = b0 + tm * 8 + jb;
        *(float4*)&hp[b * 128 + tn * 8]     = make_float4(acc[jb][0], acc[jb][1], acc[jb][2], acc[jb][3]);
        *(float4*)&hp[b * 128 + tn * 8 + 4] = make_float4(acc[jb][4], acc[jb][5], acc[jb][6], acc[jb][7]);
    }
}

__global__ __launch_bounds__(256) void k_fc2(const float* fc1b, const float* fc2w, const float* fc2b,
                                             float* ws, float* out) {
    __shared__ float hs[8][128];
    __shared__ float w2s[64][129];
    int t = threadIdx.x;
    int b0 = blockIdx.x * 8;
    const float* hp = ws + OFF_HP;
#pragma unroll
    for (int q = 0; q < 4; ++q) {
        int idx = q * 256 + t;
        int bb = idx >> 7, c = idx & 127;
        float s = fc1b[c];
#pragma unroll 8
        for (int kz = 0; kz < 64; ++kz) s += hp[kz * 262144 + (b0 + bb) * 128 + c];
        hs[bb][c] = gelu_f(s);
    }
#pragma unroll
    for (int q = 0; q < 32; ++q) {
        int idx = q * 256 + t;
        w2s[idx >> 7][idx & 127] = fc2w[idx];
    }
    __syncthreads();
#pragma unroll
    for (int q = 0; q < 2; ++q) {
        int idx = q * 256 + t;
        int bb = idx >> 6, u = idx & 63;
        float acc = fc2b[u];
#pragma unroll 8
        for (int c = 0; c < 128; ++c) acc += hs[bb][c] * w2s[u][c];
        out[(b0 + bb) * 64 + u] = acc;
    }
}

extern "C" void kernel_launch(void* const* d_in, const int* in_sizes, int n_in,
                              void* d_out, int out_size, void* d_ws, size_t ws_size,
                              hipStream_t stream) {
    const float* X1   = (const float*)d_in[0];
    const float* fc0w = (const float*)d_in[1];
    const float* fc0b = (const float*)d_in[2];
    const float* s0r  = (const float*)d_in[3];
    const float* s0i  = (const float*)d_in[4];
    const float* s1r  = (const float*)d_in[5];
    const float* s1i  = (const float*)d_in[6];
    const float* s2r  = (const float*)d_in[7];
    const float* s2i  = (const float*)d_in[8];
    const float* s3r  = (const float*)d_in[9];
    const float* s3i  = (const float*)d_in[10];
    const float* w0w  = (const float*)d_in[11];
    const float* w0b  = (const float*)d_in[12];
    const float* w1w  = (const float*)d_in[13];
    const float* w1b  = (const float*)d_in[14];
    const float* w2w  = (const float*)d_in[15];
    const float* w2b  = (const float*)d_in[16];
    const float* w3w  = (const float*)d_in[17];
    const float* w3b  = (const float*)d_in[18];
    const float* fc1w = (const float*)d_in[19];
    const float* fc1b = (const float*)d_in[20];
    const float* fc2w = (const float*)d_in[21];
    const float* fc2b = (const float*)d_in[22];
    float* ws  = (float*)d_ws;
    float* out = (float*)d_out;

    k_setup<<<dim3(16), dim3(256), 0, stream>>>(ws);
    k_transpose<<<dim3(3072), dim3(256), 0, stream>>>(s1r, s1i, s2r, s2i, s3r, s3i, ws);
    k_fc0<<<dim3(128), dim3(256), 0, stream>>>(X1, fc0w, fc0b, ws);
    k_layer0<<<dim3(2048), dim3(256), 0, stream>>>(s0r, s0i, w0w, w0b, ws);
    k_prep2<<<dim3(208), dim3(256), 0, stream>>>(w1w, w2w, w3w, ws);

    const float* pwb[3] = {w1b, w2b, w3b};
    for (int lay = 0; lay < 3; ++lay) {
        k_dft<<<dim3(1024), dim3(128), 0, stream>>>(ws);
        k_modemix<<<dim3(32, 16), dim3(256), 0, stream>>>(lay, ws);
        const float* pwt = ws + OFF_PWT + (unsigned)lay * 16384u;
        if (lay < 2)
            k_layerB<1><<<dim3(2048), dim3(256), 0, stream>>>(pwt, pwb[lay], ws);
        else
            k_layerB<0><<<dim3(2048), dim3(256), 0, stream>>>(pwt, pwb[lay], ws);
    }

    k_fc12<<<dim3(16, 64), dim3(256), 0, stream>>>(fc1w, ws);
    k_fc2<<<dim3(256), dim3(256), 0, stream>>>(fc1b, fc2w, fc2b, ws, out);
}

// Round 9
// 1058.715 us; speedup vs baseline: 1.0732x; 1.0732x over previous
//
#include <hip/hip_runtime.h>
#include <math.h>

#define PI_D 3.14159265358979323846

// ---- workspace float offsets ----
#define OFF_TW   0u
#define OFF_X0   4096u
#define OFF_PWT  OFF_X0                           // alias: X0 dead after k_layer0; 3*16384
#define OFF_TWT  (OFF_X0 + 49152u)                // 32*128, also inside X0 region
#define OFF_WT   (OFF_X0 + 262144u)
#define OFF_XFR  (OFF_WT + 1572864u)
#define OFF_XFI  (OFF_XFR + 4194304u)
#define OFF_OFR  (OFF_XFI + 4194304u)
#define OFF_OFI  (OFF_OFR + 4194304u)
#define OFF_A    (OFF_OFI + 4194304u)
#define OFF_HP   OFF_XFR                          // 64 * 262144 floats, spans XFR..A

__device__ __forceinline__ float gelu_f(float x) {
    return 0.5f * x * (1.0f + erff(x * 0.7071067811865476f));
}

// XOR bank swizzle: float4-chunk index c4 -> float column of its swizzled slot.
__device__ __forceinline__ int swzc(int c4) { return 4 * (c4 ^ ((c4 >> 3) & 3)); }

__global__ void k_setup(float* ws) {
    int id = blockIdx.x * 256 + threadIdx.x;
    if (id < 4096) {
        int l = id >> 5, c = id & 31, m = c & 15;
        double ang = (PI_D / 64.0) * (double)((m * l) & 127);
        double v = (c < 16) ? cos(ang) : -sin(ang);
        ws[OFF_TW + id] = (float)v;
    }
}

__global__ void k_transpose(const float* w1r, const float* w1i,
                            const float* w2r, const float* w2i,
                            const float* w3r, const float* w3i, float* ws) {
    int id = blockIdx.x * 256 + threadIdx.x;
    int lay = id >> 18;
    int rem = id & 262143;
    int m = rem >> 14, i = (rem >> 7) & 127, o = rem & 127;
    const float* sr = (lay == 0) ? w1r : (lay == 1) ? w2r : w3r;
    const float* si = (lay == 0) ? w1i : (lay == 1) ? w2i : w3i;
    int src = (i * 128 + o) * 16 + m;
    ws[OFF_WT + (unsigned)lay * 524288u + rem] = sr[src];
    ws[OFF_WT + (unsigned)lay * 524288u + 262144u + rem] = si[src];
}

// After k_layer0 (X0 dead): pwT[lay][i][o] = w[o][i]; TWT[c][l] = TW[l][c]
__global__ void k_prep2(const float* w1w, const float* w2w, const float* w3w, float* ws) {
    int id = blockIdx.x * 256 + threadIdx.x;
    if (id < 49152) {
        int lay = id >> 14, rem = id & 16383;
        int i = rem >> 7, o = rem & 127;
        const float* w = (lay == 0) ? w1w : (lay == 1) ? w2w : w3w;
        ws[OFF_PWT + id] = w[o * 128 + i];
    } else if (id < 53248) {
        int id2 = id - 49152;
        int c = id2 >> 7, l = id2 & 127;
        ws[OFF_TWT + c * 128 + l] = ws[OFF_TW + l * 32 + c];
    }
}

__global__ __launch_bounds__(256) void k_fc0(const float* X1, const float* w, const float* bias, float* ws) {
    __shared__ float xs[16][128];
    __shared__ float wsm[128][129];
    int t = threadIdx.x;
    int b0 = blockIdx.x * 16;
#pragma unroll
    for (int q = 0; q < 8; ++q) {
        int idx = q * 256 + t;
        xs[idx >> 7][idx & 127] = X1[b0 * 128 + idx];
    }
#pragma unroll
    for (int q = 0; q < 64; ++q) {
        int idx = q * 256 + t;
        wsm[idx >> 7][idx & 127] = w[idx];
    }
    __syncthreads();
    int c = t & 127, bh = t >> 7;
    float* x0 = ws + OFF_X0;
    for (int j = 0; j < 8; ++j) {
        int b = bh * 8 + j;
        float acc = bias[c];
#pragma unroll 8
        for (int k = 0; k < 128; ++k) acc += xs[b][k] * wsm[c][k];
        x0[(b0 + b) * 128 + c] = acc;
    }
}

__global__ __launch_bounds__(256) void k_layer0(const float* w0r, const float* w0i,
                                                const float* w0w, const float* w0b, float* ws) {
    __shared__ float x0s[128];
    __shared__ float tws[128][33];
    __shared__ float xrs[16], xis[16];
    __shared__ __align__(16) float ors[2048];
    __shared__ __align__(16) float ois[2048];
    int t = threadIdx.x, b = blockIdx.x;
    const float* tw = ws + OFF_TW;
    const float* x0 = ws + OFF_X0;
    if (t < 128) x0s[t] = x0[b * 128 + t];
#pragma unroll
    for (int q = 0; q < 16; ++q) {
        int idx = q * 256 + t;
        tws[idx >> 5][idx & 31] = tw[idx];
    }
    __syncthreads();
    if (t < 32) {
        float acc = 0.f;
        for (int l = 0; l < 128; ++l) acc += x0s[l] * tws[l][t];
        if (t < 16) xrs[t] = acc; else xis[t - 16] = acc;
    }
    __syncthreads();
#pragma unroll
    for (int q = 0; q < 8; ++q) {
        int idx = q * 256 + t;
        int m = idx & 15;
        float wr = w0r[idx], wi = w0i[idx];
        float sc = (m == 0) ? (1.f / 128.f) : (2.f / 128.f);
        float xr = xrs[m], xi = xis[m];
        ors[idx] = (xr * wr - xi * wi) * sc;
        ois[idx] = (xr * wi + xi * wr) * sc;
    }
    __syncthreads();
    int l = t & 127, og = t >> 7;
    float tvc[16], tvs[16];
#pragma unroll
    for (int m = 0; m < 16; ++m) { tvc[m] = tws[l][m]; tvs[m] = tws[l][16 + m]; }
    float xl = x0s[l];
    float* A = ws + OFF_A + b * 16384;
    const float4* or4 = (const float4*)ors;
    const float4* oi4 = (const float4*)ois;
    for (int oj = 0; oj < 64; ++oj) {
        int o = og * 64 + oj;
        float acc = xl * w0w[o] + w0b[o];
#pragma unroll
        for (int q = 0; q < 4; ++q) {
            float4 r4 = or4[o * 4 + q];
            float4 i4 = oi4[o * 4 + q];
            acc += r4.x * tvc[4 * q + 0] + i4.x * tvs[4 * q + 0];
            acc += r4.y * tvc[4 * q + 1] + i4.y * tvs[4 * q + 1];
            acc += r4.z * tvc[4 * q + 2] + i4.z * tvs[4 * q + 2];
            acc += r4.w * tvc[4 * q + 3] + i4.w * tvs[4 * q + 3];
        }
        A[o * 128 + l] = gelu_f(acc);
    }
}

// DFT GEMM: 256 rows x 32 cols per block, 256 threads, 8 rows x 4 cols per thread.
__global__ __launch_bounds__(256) void k_dft(float* ws) {
    __shared__ float as_[16][260];
    __shared__ float tws_[16][32];
    int t = threadIdx.x;
    int row0 = blockIdx.x * 256;
    const float* A = ws + OFF_A;
    const float* tw = ws + OFF_TW;
    int tr = t >> 3, tc = t & 7;               // rows tr*8..+7, cols tc*4..+3
    float acc[8][4];
#pragma unroll
    for (int j = 0; j < 8; ++j)
#pragma unroll
        for (int cc = 0; cc < 4; ++cc) acc[j][cc] = 0.f;
    int col0 = swzc(2 * tr), col1 = swzc(2 * tr + 1);
    for (int kc = 0; kc < 8; ++kc) {
        int k0 = kc * 16;
        if (kc) __syncthreads();
#pragma unroll
        for (int q = 0; q < 4; ++q) {
            int idx = q * 256 + t;
            int r = idx >> 2, kq = idx & 3;
            float4 v = *(const float4*)&A[(row0 + r) * 128 + k0 + 4 * kq];
            int sc = swzc(r >> 2) + (r & 3);
            as_[4 * kq + 0][sc] = v.x; as_[4 * kq + 1][sc] = v.y;
            as_[4 * kq + 2][sc] = v.z; as_[4 * kq + 3][sc] = v.w;
        }
#pragma unroll
        for (int q = 0; q < 2; ++q) {
            int idx = q * 256 + t;
            tws_[idx >> 5][idx & 31] = tw[(k0 + (idx >> 5)) * 32 + (idx & 31)];
        }
        __syncthreads();
#pragma unroll 8
        for (int kk = 0; kk < 16; ++kk) {
            float4 a0 = *(const float4*)&as_[kk][col0];
            float4 a1 = *(const float4*)&as_[kk][col1];
            float4 t0 = *(const float4*)&tws_[kk][tc * 4];
            float av[8] = {a0.x,a0.y,a0.z,a0.w,a1.x,a1.y,a1.z,a1.w};
            float tv[4] = {t0.x,t0.y,t0.z,t0.w};
#pragma unroll
            for (int j = 0; j < 8; ++j)
#pragma unroll
                for (int cc = 0; cc < 4; ++cc) acc[j][cc] += av[j] * tv[cc];
        }
    }
    float* xfr = ws + OFF_XFR;
    float* xfi = ws + OFF_XFI;
#pragma unroll
    for (int cc = 0; cc < 4; ++cc) {
        int c = tc * 4 + cc;
        float* dst = (c < 16) ? (xfr + c * 262144) : (xfi + (c - 16) * 262144);
        float4 v0 = make_float4(acc[0][cc], acc[1][cc], acc[2][cc], acc[3][cc]);
        float4 v1 = make_float4(acc[4][cc], acc[5][cc], acc[6][cc], acc[7][cc]);
        *(float4*)&dst[row0 + tr * 8] = v0;
        *(float4*)&dst[row0 + tr * 8 + 4] = v1;
    }
}

// Per-mode complex GEMM: 32 b x 128 o per block, 4x4 complex per thread, 16-k chunks.
// LDS 21.5 KB: x [16][36] (k x b, broadcast reads), w [16][132] (k x o, full-span reads).
__global__ __launch_bounds__(256) void k_modemix(int lay, float* ws) {
    __shared__ float xr_s[16 * 36], xi_s[16 * 36];
    __shared__ float wr_s[16 * 132], wi_s[16 * 132];
    int t = threadIdx.x;
    int b0 = blockIdx.x * 32;
    int m = blockIdx.y;
    const float* xfr = ws + OFF_XFR + m * 262144;
    const float* xfi = ws + OFF_XFI + m * 262144;
    const float* wtr = ws + OFF_WT + (unsigned)lay * 524288u + m * 16384;
    const float* wti = wtr + 262144;
    int tb = t >> 5;                   // 0..7  -> b = tb*4 + jb
    int tc = t & 31;                   // 0..31 -> o = tc*4 + jc
    int sr = (t & 127) >> 2, skq = t & 3;
    float accr[4][4], acci[4][4];
#pragma unroll
    for (int jb = 0; jb < 4; ++jb)
#pragma unroll
        for (int jc = 0; jc < 4; ++jc) { accr[jb][jc] = 0.f; acci[jb][jc] = 0.f; }
    for (int kc = 0; kc < 8; ++kc) {
        int k0 = kc * 16;
        if (kc) __syncthreads();
        {
            const float* src = (t < 128) ? xfr : xfi;
            float* dst = (t < 128) ? xr_s : xi_s;
            float4 v = *(const float4*)&src[(b0 + sr) * 128 + k0 + 4 * skq];
            dst[(4 * skq + 0) * 36 + sr] = v.x;
            dst[(4 * skq + 1) * 36 + sr] = v.y;
            dst[(4 * skq + 2) * 36 + sr] = v.z;
            dst[(4 * skq + 3) * 36 + sr] = v.w;
        }
#pragma unroll
        for (int q = 0; q < 2; ++q) {
            int idx = q * 256 + t;
            int kk = idx >> 5, oq = idx & 31;
            *(float4*)&wr_s[kk * 132 + 4 * oq] = *(const float4*)&wtr[(k0 + kk) * 128 + 4 * oq];
            *(float4*)&wi_s[kk * 132 + 4 * oq] = *(const float4*)&wti[(k0 + kk) * 128 + 4 * oq];
        }
        __syncthreads();
#pragma unroll 4
        for (int kk = 0; kk < 16; ++kk) {
            float4 xr4 = *(const float4*)&xr_s[kk * 36 + tb * 4];
            float4 xi4 = *(const float4*)&xi_s[kk * 36 + tb * 4];
            float4 wr4 = *(const float4*)&wr_s[kk * 132 + 4 * tc];
            float4 wi4 = *(const float4*)&wi_s[kk * 132 + 4 * tc];
            float xrv[4] = {xr4.x, xr4.y, xr4.z, xr4.w};
            float xiv[4] = {xi4.x, xi4.y, xi4.z, xi4.w};
            float wrv[4] = {wr4.x, wr4.y, wr4.z, wr4.w};
            float wiv[4] = {wi4.x, wi4.y, wi4.z, wi4.w};
#pragma unroll
            for (int jb = 0; jb < 4; ++jb)
#pragma unroll
                for (int jc = 0; jc < 4; ++jc) {
                    accr[jb][jc] += xrv[jb] * wrv[jc] - xiv[jb] * wiv[jc];
                    acci[jb][jc] += xrv[jb] * wiv[jc] + xiv[jb] * wrv[jc];
                }
        }
    }
    float* ofr = ws + OFF_OFR + m * 262144;
    float* ofi = ws + OFF_OFI + m * 262144;
#pragma unroll
    for (int jb = 0; jb < 4; ++jb) {
        int b = b0 + tb * 4 + jb;
        *(float4*)&ofr[b * 128 + 4 * tc] = make_float4(accr[jb][0], accr[jb][1], accr[jb][2], accr[jb][3]);
        *(float4*)&ofi[b * 128 + 4 * tc] = make_float4(acci[jb][0], acci[jb][1], acci[jb][2], acci[jb][3]);
    }
}

// iDFT (prologue, acc init) + pointwise GEMM + bias (+gelu), in-place over A. (R6 version)
template <int GELU>
__global__ __launch_bounds__(256) void k_layerB(const float* pwt, const float* pw_b, float* ws) {
    __shared__ float smem[8448];
    int t = threadIdx.x, b = blockIdx.x;
    float* A = ws + OFF_A + (unsigned)b * 16384u;
    const float* ofr = ws + OFF_OFR;
    const float* ofi = ws + OFF_OFI;
    const float* twt = ws + OFF_TWT;
    int ty = t >> 4, tx = t & 15;
    int col0 = swzc(2 * tx), col1 = swzc(2 * tx + 1);
    float* ofr_s = smem;                            // [16][128]
    float* ofi_s = smem + 2048;                     // [16][128]
    float* twTs  = smem + 4096;                     // [32][132] swizzled
#pragma unroll
    for (int q = 0; q < 2; ++q) {
        int idx = q * 256 + t;
        int mm = idx >> 5, oq = idx & 31;
        float sc = (mm == 0) ? (1.f / 128.f) : (2.f / 128.f);
        float4 vr = *(const float4*)&ofr[mm * 262144 + b * 128 + 4 * oq];
        float4 vi = *(const float4*)&ofi[mm * 262144 + b * 128 + 4 * oq];
        vr.x *= sc; vr.y *= sc; vr.z *= sc; vr.w *= sc;
        vi.x *= sc; vi.y *= sc; vi.z *= sc; vi.w *= sc;
        *(float4*)&ofr_s[mm * 128 + 4 * oq] = vr;
        *(float4*)&ofi_s[mm * 128 + 4 * oq] = vi;
    }
#pragma unroll
    for (int q = 0; q < 4; ++q) {
        int idx = q * 256 + t;
        int row = idx >> 5, c4 = idx & 31;
        *(float4*)&twTs[row * 132 + swzc(c4)] = *(const float4*)&twt[row * 128 + 4 * c4];
    }
    __syncthreads();
    float acc[8][8];
#pragma unroll
    for (int jo = 0; jo < 8; ++jo)
#pragma unroll
        for (int jl = 0; jl < 8; ++jl) acc[jo][jl] = 0.f;
#pragma unroll 2
    for (int m = 0; m < 16; ++m) {
        float4 or0 = *(const float4*)&ofr_s[m * 128 + ty * 8];
        float4 or1 = *(const float4*)&ofr_s[m * 128 + ty * 8 + 4];
        float4 oi0 = *(const float4*)&ofi_s[m * 128 + ty * 8];
        float4 oi1 = *(const float4*)&ofi_s[m * 128 + ty * 8 + 4];
        float4 c0 = *(const float4*)&twTs[m * 132 + col0];
        float4 c1 = *(const float4*)&twTs[m * 132 + col1];
        float4 s0 = *(const float4*)&twTs[(16 + m) * 132 + col0];
        float4 s1 = *(const float4*)&twTs[(16 + m) * 132 + col1];
        float orv[8] = {or0.x,or0.y,or0.z,or0.w,or1.x,or1.y,or1.z,or1.w};
        float oiv[8] = {oi0.x,oi0.y,oi0.z,oi0.w,oi1.x,oi1.y,oi1.z,oi1.w};
        float cv[8]  = {c0.x,c0.y,c0.z,c0.w,c1.x,c1.y,c1.z,c1.w};
        float sv[8]  = {s0.x,s0.y,s0.z,s0.w,s1.x,s1.y,s1.z,s1.w};
#pragma unroll
        for (int jo = 0; jo < 8; ++jo)
#pragma unroll
            for (int jl = 0; jl < 8; ++jl) acc[jo][jl] += orv[jo] * cv[jl] + oiv[jo] * sv[jl];
    }
    __syncthreads();
    float* as_ = smem;                              // [32][132] swizzled cols (l)
    float* wsx = smem + 4224;                       // [32][132] linear cols (o)
    for (int ch = 0; ch < 4; ++ch) {
        int i0 = ch * 32;
        if (ch) __syncthreads();
#pragma unroll
        for (int q = 0; q < 4; ++q) {
            int idx = q * 256 + t;
            int ic = idx >> 5, lq = idx & 31;
            *(float4*)&as_[ic * 132 + swzc(lq)] = *(const float4*)&A[(i0 + ic) * 128 + 4 * lq];
        }
#pragma unroll
        for (int q = 0; q < 4; ++q) {
            int idx = q * 256 + t;
            int ic = idx >> 5, oq = idx & 31;
            *(float4*)&wsx[ic * 132 + 4 * oq] = *(const float4*)&pwt[(i0 + ic) * 128 + 4 * oq];
        }
        __syncthreads();
#pragma unroll 4
        for (int ic = 0; ic < 32; ++ic) {
            float4 a0 = *(const float4*)&as_[ic * 132 + col0];
            float4 a1 = *(const float4*)&as_[ic * 132 + col1];
            float4 w0 = *(const float4*)&wsx[ic * 132 + ty * 8];
            float4 w1 = *(const float4*)&wsx[ic * 132 + ty * 8 + 4];
            float av[8] = {a0.x,a0.y,a0.z,a0.w,a1.x,a1.y,a1.z,a1.w};
            float wv[8] = {w0.x,w0.y,w0.z,w0.w,w1.x,w1.y,w1.z,w1.w};
#pragma unroll
            for (int jo = 0; jo < 8; ++jo)
#pragma unroll
                for (int jl = 0; jl < 8; ++jl) acc[jo][jl] += wv[jo] * av[jl];
        }
    }
#pragma unroll
    for (int jo = 0; jo < 8; ++jo) {
        int o = ty * 8 + jo;
        float bv = pw_b[o];
        float v[8];
#pragma unroll
        for (int jl = 0; jl < 8; ++jl) {
            float x = acc[jo][jl] + bv;
            v[jl] = GELU ? gelu_f(x) : x;
        }
        *(float4*)&A[o * 128 + tx * 8]     = make_float4(v[0], v[1], v[2], v[3]);
        *(float4*)&A[o * 128 + tx * 8 + 4] = make_float4(v[4], v[5], v[6], v[7]);
    }
}

// fc1 split-K: 128x128 tile, 8x8/thread, split-K=64; single-buffer 32-k chunks, both swizzled.
__global__ __launch_bounds__(256) void k_fc12(const float* fc1w, float* ws) {
    __shared__ float smem[8448];                    // a [32][132] @0, w [32][132] @4224
    int t = threadIdx.x;
    int b0 = blockIdx.x * 128;
    int kz = blockIdx.y;
    const float* A = ws + OFF_A;
    int tm = t >> 4, tn = t & 15;
    int ac0 = swzc(2 * tm), ac1 = swzc(2 * tm + 1);
    int wc0 = swzc(2 * tn), wc1 = swzc(2 * tn + 1);
    float acc[8][8];
#pragma unroll
    for (int jb = 0; jb < 8; ++jb)
#pragma unroll
        for (int jc = 0; jc < 8; ++jc) acc[jb][jc] = 0.f;
    for (int ks = 0; ks < 8; ++ks) {
        int k0 = kz * 256 + ks * 32;
        if (ks) __syncthreads();
#pragma unroll
        for (int q = 0; q < 4; ++q) {
            int idx = q * 256 + t;
            int r = idx >> 3, kq = idx & 7;
            float4 v = *(const float4*)&A[(b0 + r) * 16384 + k0 + 4 * kq];
            int sl = swzc(r >> 2) + (r & 3);
            smem[(4*kq+0)*132 + sl] = v.x; smem[(4*kq+1)*132 + sl] = v.y;
            smem[(4*kq+2)*132 + sl] = v.z; smem[(4*kq+3)*132 + sl] = v.w;
        }
#pragma unroll
        for (int q = 0; q < 4; ++q) {
            int idx = q * 256 + t;
            int c = idx >> 3, kq = idx & 7;
            float4 v = *(const float4*)&fc1w[c * 16384 + k0 + 4 * kq];
            int sl = swzc(c >> 2) + (c & 3);
            smem[4224 + (4*kq+0)*132 + sl] = v.x; smem[4224 + (4*kq+1)*132 + sl] = v.y;
            smem[4224 + (4*kq+2)*132 + sl] = v.z; smem[4224 + (4*kq+3)*132 + sl] = v.w;
        }
        __syncthreads();
#pragma unroll 4
        for (int kk = 0; kk < 32; ++kk) {
            float4 a0 = *(const float4*)&smem[kk * 132 + ac0];
            float4 a1 = *(const float4*)&smem[kk * 132 + ac1];
            float4 w0 = *(const float4*)&smem[4224 + kk * 132 + wc0];
            float4 w1 = *(const float4*)&smem[4224 + kk * 132 + wc1];
            float av[8] = {a0.x,a0.y,a0.z,a0.w,a1.x,a1.y,a1.z,a1.w};
            float wv[8] = {w0.x,w0.y,w0.z,w0.w,w1.x,w1.y,w1.z,w1.w};
#pragma unroll
            for (int jb = 0; jb < 8; ++jb)
#pragma unroll
                for (int jc = 0; jc < 8; ++jc) acc[jb][jc] += av[jb] * wv[jc];
        }
    }
    float* hp = ws + OFF_HP + kz * 262144;
#pragma unroll
    for (int jb = 0; jb < 8; ++jb) {
        int b = b0 + tm * 8 + jb;
        *(float4*)&hp[b * 128 + tn * 8]     = make_float4(acc[jb][0], acc[jb][1], acc[jb][2], acc[jb][3]);
        *(float4*)&hp[b * 128 + tn * 8 + 4] = make_float4(acc[jb][4], acc[jb][5], acc[jb][6], acc[jb][7]);
    }
}

__global__ __launch_bounds__(256) void k_fc2(const float* fc1b, const float* fc2w, const float* fc2b,
                                             float* ws, float* out) {
    __shared__ float hs[8][128];
    __shared__ float w2s[64][129];
    int t = threadIdx.x;
    int b0 = blockIdx.x * 8;
    const float* hp = ws + OFF_HP;
#pragma unroll
    for (int q = 0; q < 4; ++q) {
        int idx = q * 256 + t;
        int bb = idx >> 7, c = idx & 127;
        float s = fc1b[c];
#pragma unroll 8
        for (int kz = 0; kz < 64; ++kz) s += hp[kz * 262144 + (b0 + bb) * 128 + c];
        hs[bb][c] = gelu_f(s);
    }
#pragma unroll
    for (int q = 0; q < 32; ++q) {
        int idx = q * 256 + t;
        w2s[idx >> 7][idx & 127] = fc2w[idx];
    }
    __syncthreads();
#pragma unroll
    for (int q = 0; q < 2; ++q) {
        int idx = q * 256 + t;
        int bb = idx >> 6, u = idx & 63;
        float acc = fc2b[u];
#pragma unroll 8
        for (int c = 0; c < 128; ++c) acc += hs[bb][c] * w2s[u][c];
        out[(b0 + bb) * 64 + u] = acc;
    }
}

extern "C" void kernel_launch(void* const* d_in, const int* in_sizes, int n_in,
                              void* d_out, int out_size, void* d_ws, size_t ws_size,
                              hipStream_t stream) {
    const float* X1   = (const float*)d_in[0];
    const float* fc0w = (const float*)d_in[1];
    const float* fc0b = (const float*)d_in[2];
    const float* s0r  = (const float*)d_in[3];
    const float* s0i  = (const float*)d_in[4];
    const float* s1r  = (const float*)d_in[5];
    const float* s1i  = (const float*)d_in[6];
    const float* s2r  = (const float*)d_in[7];
    const float* s2i  = (const float*)d_in[8];
    const float* s3r  = (const float*)d_in[9];
    const float* s3i  = (const float*)d_in[10];
    const float* w0w  = (const float*)d_in[11];
    const float* w0b  = (const float*)d_in[12];
    const float* w1w  = (const float*)d_in[13];
    const float* w1b  = (const float*)d_in[14];
    const float* w2w  = (const float*)d_in[15];
    const float* w2b  = (const float*)d_in[16];
    const float* w3w  = (const float*)d_in[17];
    const float* w3b  = (const float*)d_in[18];
    const float* fc1w = (const float*)d_in[19];
    const float* fc1b = (const float*)d_in[20];
    const float* fc2w = (const float*)d_in[21];
    const float* fc2b = (const float*)d_in[22];
    float* ws  = (float*)d_ws;
    float* out = (float*)d_out;

    k_setup<<<dim3(16), dim3(256), 0, stream>>>(ws);
    k_transpose<<<dim3(3072), dim3(256), 0, stream>>>(s1r, s1i, s2r, s2i, s3r, s3i, ws);
    k_fc0<<<dim3(128), dim3(256), 0, stream>>>(X1, fc0w, fc0b, ws);
    k_layer0<<<dim3(2048), dim3(256), 0, stream>>>(s0r, s0i, w0w, w0b, ws);
    k_prep2<<<dim3(208), dim3(256), 0, stream>>>(w1w, w2w, w3w, ws);

    const float* pwb[3] = {w1b, w2b, w3b};
    for (int lay = 0; lay < 3; ++lay) {
        k_dft<<<dim3(1024), dim3(256), 0, stream>>>(ws);
        k_modemix<<<dim3(64, 16), dim3(256), 0, stream>>>(lay, ws);
        const float* pwt = ws + OFF_PWT + (unsigned)lay * 16384u;
        if (lay < 2)
            k_layerB<1><<<dim3(2048), dim3(256), 0, stream>>>(pwt, pwb[lay], ws);
        else
            k_layerB<0><<<dim3(2048), dim3(256), 0, stream>>>(pwt, pwb[lay], ws);
    }

    k_fc12<<<dim3(16, 64), dim3(256), 0, stream>>>(fc1w, ws);
    k_fc2<<<dim3(256), dim3(256), 0, stream>>>(fc1b, fc2w, fc2b, ws, out);
}